// Round 20
// baseline (363.199 us; speedup 1.0000x reference)
//
#include <hip/hip_runtime.h>

#define NN 50000
#define NE 1600000
#define EP (NE + NN)   // edges + self loops
#define IN_DIM 256
#define HIDD 64
#define NCLS 10
#define NBKT 196                       // destination buckets: d >> 8
#define EPB 8192                       // edges per partition block
#define NPB ((EP + EPB - 1) / EPB)     // 202 partition blocks
#define BCAP 12288                     // fixed bucket capacity (exp 8418 +- 92)

typedef unsigned short u16;
typedef short bf16x8 __attribute__((ext_vector_type(8)));
typedef float f32x4 __attribute__((ext_vector_type(4)));

__device__ __forceinline__ float b2f(u16 v) { return __uint_as_float(((unsigned)v) << 16); }
__device__ __forceinline__ u16 f2b(float f) {
    unsigned u = __float_as_uint(f);
    unsigned r = (u + 0x7FFFu + ((u >> 16) & 1u)) >> 16;
    return (u16)r;
}

__device__ __forceinline__ void load_edge(const int* __restrict__ ei, int m, int g,
                                          int& s, int& d) {
    if (g < NE) {
        if (m) { s = ei[2 * (size_t)g]; d = ei[2 * ((size_t)NE + g)]; }
        else   { s = ei[g];             d = ei[NE + g]; }
    } else {
        s = d = g - NE;  // self loop
    }
    s = s < 0 ? 0 : (s >= NN ? NN - 1 : s);
    d = d < 0 ? 0 : (d >= NN ? NN - 1 : d);
}

// ---- weight transpose + augmented score rows (device helper) ----
__device__ __forceinline__ void wcvt_att_job(
    const float* __restrict__ W, const float* __restrict__ as,
    const float* __restrict__ ad, int K, int N, int H, u16* __restrict__ Wt,
    int idx) {
    if (idx >= K * (N + 16)) return;
    int n = idx / K, k = idx - n * K;
    if (n < N) { Wt[idx] = f2b(W[(size_t)k * N + n]); return; }
    int j = n - N;
    if (j >= 2 * H) { Wt[idx] = 0; return; }
    const float* att = (j & 1) ? ad : as;
    int h = j >> 1, C = N / H;
    float sum = 0.f;
    for (int c = 0; c < C; ++c)
        sum += W[(size_t)k * N + h * C + c] * att[h * C + c];
    Wt[idx] = f2b(sum);
}

// ---- single-pass partition into fixed-capacity bucket slots ----
// 1024 threads/block (16 waves = 4/SIMD: latency hiding). EPB unchanged.
__global__ __launch_bounds__(1024) void partition_k(
    const int* __restrict__ ei, int* __restrict__ gcursor,
    unsigned* __restrict__ bbuf,
    const float* __restrict__ W1, const float* __restrict__ as1,
    const float* __restrict__ ad1, u16* __restrict__ w1t,
    const float* __restrict__ W2, const float* __restrict__ as2,
    const float* __restrict__ ad2, u16* __restrict__ w2t) {
    __shared__ int hist[NBKT], base[NBKT], cur[NBKT];
    __shared__ unsigned stash[EPB];
    __shared__ int smode;
    int t = threadIdx.x, b = blockIdx.x;
    // side jobs: W1 on blocks 0..35 (36*1024 = 256*144), W2 on 36..45 (10*1024)
    if (b < 36) wcvt_att_job(W1, as1, ad1, 256, 128, 2, w1t, b * 1024 + t);
    else if (b < 46) wcvt_att_job(W2, as2, ad2, 128, 64, 1, w2t, (b - 36) * 1024 + t);
    // local dtype detect (wave 0)
    if (t < 64) {
        int nz = 0;
#pragma unroll
        for (int k = 0; k < 4; ++k)
            if (ei[2 * (t * 4 + k) + 1] != 0) nz = 1;
        unsigned long long bal = __ballot(nz);
        if (t == 0) smode = (bal == 0ULL) ? 1 : 0;  // 1 = int64 layout
    }
    for (int i = t; i < NBKT; i += 1024) hist[i] = 0;
    __syncthreads();
    int m = smode;
    int g0 = b * EPB;
    int gend = min(g0 + EPB, EP);
    for (int g = g0 + t; g < gend; g += 1024) {
        int s, d;
        load_edge(ei, m, g, s, d);
        stash[g - g0] = ((unsigned)s << 16) | (unsigned)d;
        atomicAdd(&hist[d >> 8], 1);
    }
    __syncthreads();
    for (int i = t; i < NBKT; i += 1024) {
        base[i] = hist[i] ? atomicAdd(&gcursor[i], hist[i]) : 0;
        cur[i] = 0;
    }
    __syncthreads();
    int cnt = gend - g0;
    for (int l = t; l < cnt; l += 1024) {
        unsigned p = stash[l];
        int d = p & 0xFFFF;
        int bb = d >> 8;
        int r = base[bb] + atomicAdd(&cur[bb], 1);
        if (r < BCAP)  // harden: adversarial skew can't write OOB
            bbuf[(size_t)bb * BCAP + r] = ((p >> 16) << 8) | (unsigned)(d & 255);
    }
}

// ---- per-bucket fine CSR (bucket-base scan fused in); 1024 threads/block ----
__global__ __launch_bounds__(1024) void bucket_csr_k(const unsigned* __restrict__ bbuf,
                                                     const int* __restrict__ gcursor,
                                                     int* __restrict__ row_ptr,
                                                     u16* __restrict__ csr_src) {
    __shared__ int bsc[256];
    __shared__ int hist[256], scn[256], cur[256];
    __shared__ int se0, scnt, stot;
    int b = blockIdx.x, t = threadIdx.x;
    int v = 0;
    if (t < 256) {
        v = (t < NBKT) ? min(gcursor[t], BCAP) : 0;
        bsc[t] = v;
        hist[t] = 0;
    }
    __syncthreads();
    for (int off = 1; off < 256; off <<= 1) {
        int x = (t < 256 && t >= off) ? bsc[t - off] : 0;
        __syncthreads();
        if (t < 256) bsc[t] += x;
        __syncthreads();
    }
    if (t == b) { se0 = bsc[t] - v; scnt = v; }
    if (t == NBKT - 1) stot = bsc[t];
    __syncthreads();
    int e0 = se0, cnt = scnt;
    const unsigned* bb = bbuf + (size_t)b * BCAP;
    for (int e = t; e < cnt; e += 1024)
        atomicAdd(&hist[bb[e] & 255], 1);
    __syncthreads();
    int hv = 0;
    if (t < 256) { hv = hist[t]; scn[t] = hv; }
    __syncthreads();
    for (int off = 1; off < 256; off <<= 1) {
        int x = (t < 256 && t >= off) ? scn[t - off] : 0;
        __syncthreads();
        if (t < 256) scn[t] += x;
        __syncthreads();
    }
    if (t < 256) {
        int ex = scn[t] - hv;  // exclusive within bucket
        int n = b * 256 + t;
        if (n < NN) row_ptr[n] = e0 + ex;
        cur[t] = e0 + ex;
    }
    __syncthreads();
    for (int e = t; e < cnt; e += 1024) {
        unsigned p = bb[e];
        int pos = atomicAdd(&cur[p & 255], 1);
        csr_src[pos] = (u16)(p >> 8);
    }
    if (b == 0 && t == 0) row_ptr[NN] = stot;
}

// ---- MFMA GEMM + fused scores ----
template <int K, int NF, int H, bool F32A>
__global__ __launch_bounds__(256) void gemm_mfma_att_k(
    const float* __restrict__ Af, const u16* __restrict__ Ab,
    const u16* __restrict__ Wt, u16* __restrict__ C,
    float* __restrict__ a_s, float* __restrict__ a_d) {
    constexpr int NTF = NF / 16, NT = NTF + 1, KS = K / 32;
    const int wave = threadIdx.x >> 6, lane = threadIdx.x & 63;
    const int quad = lane >> 4, l15 = lane & 15;
    const int m0 = blockIdx.x * 64 + wave * 16;
    int rowA = m0 + l15;
    if (rowA >= NN) rowA = NN - 1;
    const float* afp = F32A ? (Af + (size_t)rowA * K + quad * 8) : nullptr;
    const u16*   abp = F32A ? nullptr : (Ab + (size_t)rowA * K + quad * 8);
    const u16* bptr = Wt + (size_t)l15 * K + quad * 8;
    f32x4 acc[NT] = {};
#pragma unroll
    for (int ks = 0; ks < KS; ++ks) {
        bf16x8 af;
        if (F32A) {
            float4 v0 = *(const float4*)(afp + ks * 32);
            float4 v1 = *(const float4*)(afp + ks * 32 + 4);
            af[0] = (short)f2b(v0.x); af[1] = (short)f2b(v0.y);
            af[2] = (short)f2b(v0.z); af[3] = (short)f2b(v0.w);
            af[4] = (short)f2b(v1.x); af[5] = (short)f2b(v1.y);
            af[6] = (short)f2b(v1.z); af[7] = (short)f2b(v1.w);
        } else {
            af = *(const bf16x8*)(abp + ks * 32);
        }
        bf16x8 bf[NT];
#pragma unroll
        for (int nt = 0; nt < NT; ++nt)
            bf[nt] = *(const bf16x8*)(bptr + (size_t)nt * 16 * K + ks * 32);
#pragma unroll
        for (int nt = 0; nt < NT; ++nt)
            acc[nt] = __builtin_amdgcn_mfma_f32_16x16x32_bf16(af, bf[nt], acc[nt], 0, 0, 0);
    }
#pragma unroll
    for (int nt = 0; nt < NTF; ++nt) {
#pragma unroll
        for (int reg = 0; reg < 4; ++reg) {
            int row = m0 + quad * 4 + reg;
            if (row < NN) C[(size_t)row * NF + nt * 16 + l15] = f2b(acc[nt][reg]);
        }
    }
    if (l15 < 2 * H) {
        int h = l15 >> 1;
        float* dst = (l15 & 1) ? a_d : a_s;
#pragma unroll
        for (int reg = 0; reg < 4; ++reg) {
            int row = m0 + quad * 4 + reg;
            if (row < NN) dst[row * H + h] = acc[NTF][reg];
        }
    }
}

// ---- fused gather (bf16 h): one WAVE per node; VEC = CH/64 bf16 per lane ----
// Lane-parallel exp; JB=24 j-loop via v_readlane (SGPR broadcasts). JB ladder:
// 8@VGPR24 -> 85us, 16@VGPR16 -> 66us (r18); 24 costs ~+8 VGPR, still 8
// waves/SIMD. ex numerator rounded to bf16 (~0.2%).
template <int CH, int H, bool HEAD>
__global__ __launch_bounds__(256) void gat_gather_k(
    const int* __restrict__ row_ptr, const u16* __restrict__ csr_src,
    const float* __restrict__ a_s, const float* __restrict__ a_d,
    const u16* __restrict__ h, const float* __restrict__ bias,
    u16* __restrict__ outg, const float* __restrict__ Wl,
    const float* __restrict__ bl, float* __restrict__ outh) {
    constexpr int VEC = CH / 64;
    constexpr int JB = 24;
    int n = (blockIdx.x * blockDim.x + threadIdx.x) >> 6;  // global wave id = node
    int lane = threadIdx.x & 63;
    if (n >= NN) return;  // wave-uniform exit
    int r0 = row_ptr[n], r1 = row_ptr[n + 1];
    const bool hi = (VEC == 2) ? (lane >= 32) : false;
    const int shl16 = hi ? 0 : 16;  // select my head's bf16 ex into bits 31..16

    float adn0, adn1 = 0.f;
    if (H == 2) {
        float2 adv = *(const float2*)(a_d + n * 2);
        adn0 = adv.x; adn1 = adv.y;
    } else {
        adn0 = a_d[n];
    }

    float dh0 = 0.f, dh1 = 0.f;
    float acc[VEC];
#pragma unroll
    for (int v = 0; v < VEC; ++v) acc[v] = 0.f;

    for (int base = r0; base < r1; base += 64) {
        int cnt = min(64, r1 - base);
        int idx = base + lane;
        bool act = idx < r1;
        int sl = act ? (int)csr_src[idx] : 0;
        unsigned pex;   // H==2: bf16(ex0)|bf16(ex1)<<16 ; H==1: s|bf16(ex)<<16
        if (H == 2) {
            float2 av = *(const float2*)(a_s + sl * 2);
            float e0 = av.x + adn0;
            e0 = e0 > 0.f ? e0 : 0.2f * e0;
            e0 = fminf(e0, 60.f);
            float ex0 = act ? __expf(e0) : 0.f;
            dh0 += ex0;
            float e1 = av.y + adn1;
            e1 = e1 > 0.f ? e1 : 0.2f * e1;
            e1 = fminf(e1, 60.f);
            float ex1 = act ? __expf(e1) : 0.f;
            dh1 += ex1;
            pex = (unsigned)f2b(ex0) | ((unsigned)f2b(ex1) << 16);
        } else {
            float e0 = a_s[sl] + adn0;
            e0 = e0 > 0.f ? e0 : 0.2f * e0;
            e0 = fminf(e0, 60.f);
            float ex0 = act ? __expf(e0) : 0.f;
            dh0 += ex0;
            pex = (unsigned)sl | ((unsigned)f2b(ex0) << 16);
        }
        for (int j0 = 0; j0 < cnt; j0 += JB) {
            int jn = min(JB, cnt - j0);
            if (VEC == 2) {
                int ssu[JB];
                unsigned peu[JB];
#pragma unroll
                for (int i = 0; i < JB; ++i) {
                    int j = j0 + (i < jn ? i : 0);
                    ssu[i] = __builtin_amdgcn_readlane(sl, j);
                    peu[i] = (i < jn) ? (unsigned)__builtin_amdgcn_readlane((int)pex, j) : 0u;
                }
                unsigned hv[JB];
#pragma unroll
                for (int i = 0; i < JB; ++i)
                    hv[i] = ((const unsigned*)(h + (size_t)ssu[i] * CH))[lane];
#pragma unroll
                for (int i = 0; i < JB; ++i) {
                    float exv = __uint_as_float((peu[i] << shl16) & 0xFFFF0000u);
                    acc[0] += exv * __uint_as_float(hv[i] << 16);
                    acc[1] += exv * __uint_as_float(hv[i] & 0xFFFF0000u);
                }
            } else {
                unsigned peu[JB];
#pragma unroll
                for (int i = 0; i < JB; ++i) {
                    int j = j0 + (i < jn ? i : 0);
                    unsigned p = (unsigned)__builtin_amdgcn_readlane((int)pex, j);
                    peu[i] = (i < jn) ? p : (p & 0xFFFFu);  // zero ex for pad
                }
                u16 hv[JB];
#pragma unroll
                for (int i = 0; i < JB; ++i)
                    hv[i] = (h + (size_t)(peu[i] & 0xFFFFu) * CH)[lane];
#pragma unroll
                for (int i = 0; i < JB; ++i)
                    acc[0] += __uint_as_float(peu[i] & 0xFFFF0000u) * b2f(hv[i]);
            }
        }
    }

#pragma unroll
    for (int off = 32; off; off >>= 1) dh0 += __shfl_xor(dh0, off);
    float dn = dh0;
    if (H == 2) {
#pragma unroll
        for (int off = 32; off; off >>= 1) dh1 += __shfl_xor(dh1, off);
        dn = hi ? dh1 : dh0;
    }

    if (VEC == 2) {
        int c = lane * 2;
        float2 bv = *(const float2*)(bias + c);
        float v0 = acc[0] / dn + bv.x;
        float v1 = acc[1] / dn + bv.y;
        v0 = v0 > 0.f ? v0 : expm1f(v0);
        v1 = v1 > 0.f ? v1 : expm1f(v1);
        ushort2 ov;
        ov.x = f2b(v0); ov.y = f2b(v1);
        *(ushort2*)(outg + (size_t)n * CH + c) = ov;
    } else {
        float v0 = acc[0] / dn + bias[lane];
        v0 = v0 > 0.f ? v0 : expm1f(v0);
        if (HEAD) {
#pragma unroll
            for (int cls = 0; cls < NCLS; ++cls) {
                float p = v0 * Wl[lane * NCLS + cls];
#pragma unroll
                for (int off = 32; off; off >>= 1) p += __shfl_xor(p, off);
                if (lane == cls) outh[(size_t)n * NCLS + cls] = p + bl[cls];
            }
        } else {
            outg[(size_t)n * CH + lane] = f2b(v0);
        }
    }
}

extern "C" void kernel_launch(void* const* d_in, const int* in_sizes, int n_in,
                              void* d_out, int out_size, void* d_ws, size_t ws_size,
                              hipStream_t stream) {
    const float* x   = (const float*)d_in[0];
    const int*   ei  = (const int*)d_in[1];
    const float* W1  = (const float*)d_in[2];
    const float* as1 = (const float*)d_in[3];
    const float* ad1 = (const float*)d_in[4];
    const float* b1  = (const float*)d_in[5];
    const float* W2  = (const float*)d_in[6];
    const float* as2 = (const float*)d_in[7];
    const float* ad2 = (const float*)d_in[8];
    const float* b2  = (const float*)d_in[9];
    const float* Wl  = (const float*)d_in[10];
    const float* bl  = (const float*)d_in[11];
    float* out = (float*)d_out;

    // ---- workspace layout: ~31 MB (bbuf overlays g1: 9.63 MB <= 12.8 MB) ----
    float* ws = (float*)d_ws;
    size_t o = 0;
    u16* hb  = (u16*)(ws + o); o += (size_t)NN * 64;    // bf16 h1[NN][128] / h2[NN][64]
    u16* g1  = (u16*)(ws + o); o += (size_t)NN * 64;    // bf16 g1 [NN][128]  (= bbuf space)
    unsigned* bbuf = (unsigned*)g1;
    u16* w1t = (u16*)(ws + o); o += 144 * 256 / 2;      // bf16 W1^T+att [144][256]
    u16* w2t = (u16*)(ws + o); o += 80 * 128 / 2;       // bf16 W2^T+att [80][128]
    float* a_s = ws + o;       o += (size_t)NN * 2;
    float* a_d = ws + o;       o += (size_t)NN * 2;
    int* ints = (int*)(ws + o);
    size_t io = 0;
    int* gcursor  = ints + io; io += NBKT;
    int* row_ptr  = ints + io; io += NN + 1;
    u16* csr_src  = (u16*)(ints + io); io += (EP + 1) / 2;

    // ---- CSR build: memset + single edge pass (with setup side jobs) + bucket pass
    hipMemsetAsync(gcursor, 0, NBKT * sizeof(int), stream);
    partition_k<<<NPB, 1024, 0, stream>>>(ei, gcursor, bbuf,
                                          W1, as1, ad1, w1t, W2, as2, ad2, w2t);
    bucket_csr_k<<<NBKT, 1024, 0, stream>>>(bbuf, gcursor, row_ptr, csr_src);

    const int gatherBlocks = (NN + 3) / 4;  // 4 waves (nodes) per 256-thread block
    const int gemmBlocks = (NN + 63) / 64;

    // ---- layer 1: GATConv(256 -> 64, heads=2, concat) + ELU ----
    gemm_mfma_att_k<256, 128, 2, true><<<gemmBlocks, 256, 0, stream>>>(
        x, nullptr, w1t, hb, a_s, a_d);
    gat_gather_k<128, 2, false><<<gatherBlocks, 256, 0, stream>>>(
        row_ptr, csr_src, a_s, a_d, hb, b1, g1, nullptr, nullptr, nullptr);

    // ---- layer 2: GATConv(128 -> 64, heads=1) + ELU + fused head ----
    gemm_mfma_att_k<128, 64, 1, false><<<gemmBlocks, 256, 0, stream>>>(
        nullptr, g1, w2t, hb, a_s, a_d);
    gat_gather_k<64, 1, true><<<gatherBlocks, 256, 0, stream>>>(
        row_ptr, csr_src, a_s, a_d, hb, b2, nullptr, Wl, bl, out);
}

// Round 21
// 310.497 us; speedup vs baseline: 1.1697x; 1.1697x over previous
//
#include <hip/hip_runtime.h>

#define NN 50000
#define NE 1600000
#define EP (NE + NN)   // edges + self loops
#define IN_DIM 256
#define HIDD 64
#define NCLS 10
#define NBKT 196                       // destination buckets: d >> 8
#define EPB 8192                       // edges per partition block
#define NPB ((EP + EPB - 1) / EPB)     // 202 partition blocks
#define BCAP 12288                     // fixed bucket capacity (exp 8418 +- 92)

typedef unsigned short u16;
typedef short bf16x8 __attribute__((ext_vector_type(8)));
typedef float f32x4 __attribute__((ext_vector_type(4)));

__device__ __forceinline__ float b2f(u16 v) { return __uint_as_float(((unsigned)v) << 16); }
__device__ __forceinline__ u16 f2b(float f) {
    unsigned u = __float_as_uint(f);
    unsigned r = (u + 0x7FFFu + ((u >> 16) & 1u)) >> 16;
    return (u16)r;
}

__device__ __forceinline__ void load_edge(const int* __restrict__ ei, int m, int g,
                                          int& s, int& d) {
    if (g < NE) {
        if (m) { s = ei[2 * (size_t)g]; d = ei[2 * ((size_t)NE + g)]; }
        else   { s = ei[g];             d = ei[NE + g]; }
    } else {
        s = d = g - NE;  // self loop
    }
    s = s < 0 ? 0 : (s >= NN ? NN - 1 : s);
    d = d < 0 ? 0 : (d >= NN ? NN - 1 : d);
}

// ---- weight transpose + augmented score rows (device helper) ----
__device__ __forceinline__ void wcvt_att_job(
    const float* __restrict__ W, const float* __restrict__ as,
    const float* __restrict__ ad, int K, int N, int H, u16* __restrict__ Wt,
    int idx) {
    if (idx >= K * (N + 16)) return;
    int n = idx / K, k = idx - n * K;
    if (n < N) { Wt[idx] = f2b(W[(size_t)k * N + n]); return; }
    int j = n - N;
    if (j >= 2 * H) { Wt[idx] = 0; return; }
    const float* att = (j & 1) ? ad : as;
    int h = j >> 1, C = N / H;
    float sum = 0.f;
    for (int c = 0; c < C; ++c)
        sum += W[(size_t)k * N + h * C + c] * att[h * C + c];
    Wt[idx] = f2b(sum);
}

// ---- single-pass partition into fixed-capacity bucket slots ----
// 1024 threads/block (16 waves = 4/SIMD: latency hiding). EPB unchanged.
__global__ __launch_bounds__(1024) void partition_k(
    const int* __restrict__ ei, int* __restrict__ gcursor,
    unsigned* __restrict__ bbuf,
    const float* __restrict__ W1, const float* __restrict__ as1,
    const float* __restrict__ ad1, u16* __restrict__ w1t,
    const float* __restrict__ W2, const float* __restrict__ as2,
    const float* __restrict__ ad2, u16* __restrict__ w2t) {
    __shared__ int hist[NBKT], base[NBKT], cur[NBKT];
    __shared__ unsigned stash[EPB];
    __shared__ int smode;
    int t = threadIdx.x, b = blockIdx.x;
    // side jobs: W1 on blocks 0..35 (36*1024 = 256*144), W2 on 36..45 (10*1024)
    if (b < 36) wcvt_att_job(W1, as1, ad1, 256, 128, 2, w1t, b * 1024 + t);
    else if (b < 46) wcvt_att_job(W2, as2, ad2, 128, 64, 1, w2t, (b - 36) * 1024 + t);
    // local dtype detect (wave 0)
    if (t < 64) {
        int nz = 0;
#pragma unroll
        for (int k = 0; k < 4; ++k)
            if (ei[2 * (t * 4 + k) + 1] != 0) nz = 1;
        unsigned long long bal = __ballot(nz);
        if (t == 0) smode = (bal == 0ULL) ? 1 : 0;  // 1 = int64 layout
    }
    for (int i = t; i < NBKT; i += 1024) hist[i] = 0;
    __syncthreads();
    int m = smode;
    int g0 = b * EPB;
    int gend = min(g0 + EPB, EP);
    for (int g = g0 + t; g < gend; g += 1024) {
        int s, d;
        load_edge(ei, m, g, s, d);
        stash[g - g0] = ((unsigned)s << 16) | (unsigned)d;
        atomicAdd(&hist[d >> 8], 1);
    }
    __syncthreads();
    for (int i = t; i < NBKT; i += 1024) {
        base[i] = hist[i] ? atomicAdd(&gcursor[i], hist[i]) : 0;
        cur[i] = 0;
    }
    __syncthreads();
    int cnt = gend - g0;
    for (int l = t; l < cnt; l += 1024) {
        unsigned p = stash[l];
        int d = p & 0xFFFF;
        int bb = d >> 8;
        int r = base[bb] + atomicAdd(&cur[bb], 1);
        if (r < BCAP)  // harden: adversarial skew can't write OOB
            bbuf[(size_t)bb * BCAP + r] = ((p >> 16) << 8) | (unsigned)(d & 255);
    }
}

// ---- per-bucket fine CSR (bucket-base scan fused in); 1024 threads/block ----
__global__ __launch_bounds__(1024) void bucket_csr_k(const unsigned* __restrict__ bbuf,
                                                     const int* __restrict__ gcursor,
                                                     int* __restrict__ row_ptr,
                                                     u16* __restrict__ csr_src) {
    __shared__ int bsc[256];
    __shared__ int hist[256], scn[256], cur[256];
    __shared__ int se0, scnt, stot;
    int b = blockIdx.x, t = threadIdx.x;
    int v = 0;
    if (t < 256) {
        v = (t < NBKT) ? min(gcursor[t], BCAP) : 0;
        bsc[t] = v;
        hist[t] = 0;
    }
    __syncthreads();
    for (int off = 1; off < 256; off <<= 1) {
        int x = (t < 256 && t >= off) ? bsc[t - off] : 0;
        __syncthreads();
        if (t < 256) bsc[t] += x;
        __syncthreads();
    }
    if (t == b) { se0 = bsc[t] - v; scnt = v; }
    if (t == NBKT - 1) stot = bsc[t];
    __syncthreads();
    int e0 = se0, cnt = scnt;
    const unsigned* bb = bbuf + (size_t)b * BCAP;
    for (int e = t; e < cnt; e += 1024)
        atomicAdd(&hist[bb[e] & 255], 1);
    __syncthreads();
    int hv = 0;
    if (t < 256) { hv = hist[t]; scn[t] = hv; }
    __syncthreads();
    for (int off = 1; off < 256; off <<= 1) {
        int x = (t < 256 && t >= off) ? scn[t - off] : 0;
        __syncthreads();
        if (t < 256) scn[t] += x;
        __syncthreads();
    }
    if (t < 256) {
        int ex = scn[t] - hv;  // exclusive within bucket
        int n = b * 256 + t;
        if (n < NN) row_ptr[n] = e0 + ex;
        cur[t] = e0 + ex;
    }
    __syncthreads();
    for (int e = t; e < cnt; e += 1024) {
        unsigned p = bb[e];
        int pos = atomicAdd(&cur[p & 255], 1);
        csr_src[pos] = (u16)(p >> 8);
    }
    if (b == 0 && t == 0) row_ptr[NN] = stot;
}

// ---- MFMA GEMM + fused scores ----
template <int K, int NF, int H, bool F32A>
__global__ __launch_bounds__(256) void gemm_mfma_att_k(
    const float* __restrict__ Af, const u16* __restrict__ Ab,
    const u16* __restrict__ Wt, u16* __restrict__ C,
    float* __restrict__ a_s, float* __restrict__ a_d) {
    constexpr int NTF = NF / 16, NT = NTF + 1, KS = K / 32;
    const int wave = threadIdx.x >> 6, lane = threadIdx.x & 63;
    const int quad = lane >> 4, l15 = lane & 15;
    const int m0 = blockIdx.x * 64 + wave * 16;
    int rowA = m0 + l15;
    if (rowA >= NN) rowA = NN - 1;
    const float* afp = F32A ? (Af + (size_t)rowA * K + quad * 8) : nullptr;
    const u16*   abp = F32A ? nullptr : (Ab + (size_t)rowA * K + quad * 8);
    const u16* bptr = Wt + (size_t)l15 * K + quad * 8;
    f32x4 acc[NT] = {};
#pragma unroll
    for (int ks = 0; ks < KS; ++ks) {
        bf16x8 af;
        if (F32A) {
            float4 v0 = *(const float4*)(afp + ks * 32);
            float4 v1 = *(const float4*)(afp + ks * 32 + 4);
            af[0] = (short)f2b(v0.x); af[1] = (short)f2b(v0.y);
            af[2] = (short)f2b(v0.z); af[3] = (short)f2b(v0.w);
            af[4] = (short)f2b(v1.x); af[5] = (short)f2b(v1.y);
            af[6] = (short)f2b(v1.z); af[7] = (short)f2b(v1.w);
        } else {
            af = *(const bf16x8*)(abp + ks * 32);
        }
        bf16x8 bf[NT];
#pragma unroll
        for (int nt = 0; nt < NT; ++nt)
            bf[nt] = *(const bf16x8*)(bptr + (size_t)nt * 16 * K + ks * 32);
#pragma unroll
        for (int nt = 0; nt < NT; ++nt)
            acc[nt] = __builtin_amdgcn_mfma_f32_16x16x32_bf16(af, bf[nt], acc[nt], 0, 0, 0);
    }
#pragma unroll
    for (int nt = 0; nt < NTF; ++nt) {
#pragma unroll
        for (int reg = 0; reg < 4; ++reg) {
            int row = m0 + quad * 4 + reg;
            if (row < NN) C[(size_t)row * NF + nt * 16 + l15] = f2b(acc[nt][reg]);
        }
    }
    if (l15 < 2 * H) {
        int h = l15 >> 1;
        float* dst = (l15 & 1) ? a_d : a_s;
#pragma unroll
        for (int reg = 0; reg < 4; ++reg) {
            int row = m0 + quad * 4 + reg;
            if (row < NN) dst[row * H + h] = acc[NTF][reg];
        }
    }
}

// ---- fused gather (bf16 h): one WAVE per node; VEC = CH/64 bf16 per lane ----
// Lane-parallel exp; JB=16 j-loop via v_readlane with COMPILE-TIME-CONSTANT
// lane indices (JB must divide 64: JB=24's tail select forced non-constant
// readlane indices -> VALU explosion, round 20). VGPR 16, occ ~74% (r18/19).
template <int CH, int H, bool HEAD>
__global__ __launch_bounds__(256) void gat_gather_k(
    const int* __restrict__ row_ptr, const u16* __restrict__ csr_src,
    const float* __restrict__ a_s, const float* __restrict__ a_d,
    const u16* __restrict__ h, const float* __restrict__ bias,
    u16* __restrict__ outg, const float* __restrict__ Wl,
    const float* __restrict__ bl, float* __restrict__ outh) {
    constexpr int VEC = CH / 64;
    constexpr int JB = 16;
    int n = (blockIdx.x * blockDim.x + threadIdx.x) >> 6;  // global wave id = node
    int lane = threadIdx.x & 63;
    if (n >= NN) return;  // wave-uniform exit
    int r0 = row_ptr[n], r1 = row_ptr[n + 1];
    const bool hi = (VEC == 2) ? (lane >= 32) : false;
    const int shl16 = hi ? 0 : 16;  // select my head's bf16 ex into bits 31..16

    float adn0, adn1 = 0.f;
    if (H == 2) {
        float2 adv = *(const float2*)(a_d + n * 2);
        adn0 = adv.x; adn1 = adv.y;
    } else {
        adn0 = a_d[n];
    }

    float dh0 = 0.f, dh1 = 0.f;
    float acc[VEC];
#pragma unroll
    for (int v = 0; v < VEC; ++v) acc[v] = 0.f;

    for (int base = r0; base < r1; base += 64) {
        int cnt = min(64, r1 - base);
        int idx = base + lane;
        bool act = idx < r1;
        int sl = act ? (int)csr_src[idx] : 0;
        unsigned pex;   // H==2: bf16(ex0)|bf16(ex1)<<16 ; H==1: s|bf16(ex)<<16
        if (H == 2) {
            float2 av = *(const float2*)(a_s + sl * 2);
            float e0 = av.x + adn0;
            e0 = e0 > 0.f ? e0 : 0.2f * e0;
            e0 = fminf(e0, 60.f);
            float ex0 = act ? __expf(e0) : 0.f;
            dh0 += ex0;
            float e1 = av.y + adn1;
            e1 = e1 > 0.f ? e1 : 0.2f * e1;
            e1 = fminf(e1, 60.f);
            float ex1 = act ? __expf(e1) : 0.f;
            dh1 += ex1;
            pex = (unsigned)f2b(ex0) | ((unsigned)f2b(ex1) << 16);
        } else {
            float e0 = a_s[sl] + adn0;
            e0 = e0 > 0.f ? e0 : 0.2f * e0;
            e0 = fminf(e0, 60.f);
            float ex0 = act ? __expf(e0) : 0.f;
            dh0 += ex0;
            pex = (unsigned)sl | ((unsigned)f2b(ex0) << 16);
        }
        for (int j0 = 0; j0 < cnt; j0 += JB) {
            if (VEC == 2) {
                int ssu[JB];
                unsigned peu[JB];
#pragma unroll
                for (int i = 0; i < JB; ++i) {
                    ssu[i] = __builtin_amdgcn_readlane(sl, j0 + i);
                    peu[i] = (unsigned)__builtin_amdgcn_readlane((int)pex, j0 + i);
                }
                unsigned hv[JB];
#pragma unroll
                for (int i = 0; i < JB; ++i)
                    hv[i] = ((const unsigned*)(h + (size_t)ssu[i] * CH))[lane];
#pragma unroll
                for (int i = 0; i < JB; ++i) {
                    float exv = __uint_as_float((peu[i] << shl16) & 0xFFFF0000u);
                    acc[0] += exv * __uint_as_float(hv[i] << 16);
                    acc[1] += exv * __uint_as_float(hv[i] & 0xFFFF0000u);
                }
            } else {
                unsigned peu[JB];
#pragma unroll
                for (int i = 0; i < JB; ++i)
                    peu[i] = (unsigned)__builtin_amdgcn_readlane((int)pex, j0 + i);
                u16 hv[JB];
#pragma unroll
                for (int i = 0; i < JB; ++i)
                    hv[i] = (h + (size_t)(peu[i] & 0xFFFFu) * CH)[lane];
#pragma unroll
                for (int i = 0; i < JB; ++i)
                    acc[0] += __uint_as_float(peu[i] & 0xFFFF0000u) * b2f(hv[i]);
            }
        }
    }

#pragma unroll
    for (int off = 32; off; off >>= 1) dh0 += __shfl_xor(dh0, off);
    float dn = dh0;
    if (H == 2) {
#pragma unroll
        for (int off = 32; off; off >>= 1) dh1 += __shfl_xor(dh1, off);
        dn = hi ? dh1 : dh0;
    }

    if (VEC == 2) {
        int c = lane * 2;
        float2 bv = *(const float2*)(bias + c);
        float v0 = acc[0] / dn + bv.x;
        float v1 = acc[1] / dn + bv.y;
        v0 = v0 > 0.f ? v0 : expm1f(v0);
        v1 = v1 > 0.f ? v1 : expm1f(v1);
        ushort2 ov;
        ov.x = f2b(v0); ov.y = f2b(v1);
        *(ushort2*)(outg + (size_t)n * CH + c) = ov;
    } else {
        float v0 = acc[0] / dn + bias[lane];
        v0 = v0 > 0.f ? v0 : expm1f(v0);
        if (HEAD) {
#pragma unroll
            for (int cls = 0; cls < NCLS; ++cls) {
                float p = v0 * Wl[lane * NCLS + cls];
#pragma unroll
                for (int off = 32; off; off >>= 1) p += __shfl_xor(p, off);
                if (lane == cls) outh[(size_t)n * NCLS + cls] = p + bl[cls];
            }
        } else {
            outg[(size_t)n * CH + lane] = f2b(v0);
        }
    }
}

extern "C" void kernel_launch(void* const* d_in, const int* in_sizes, int n_in,
                              void* d_out, int out_size, void* d_ws, size_t ws_size,
                              hipStream_t stream) {
    const float* x   = (const float*)d_in[0];
    const int*   ei  = (const int*)d_in[1];
    const float* W1  = (const float*)d_in[2];
    const float* as1 = (const float*)d_in[3];
    const float* ad1 = (const float*)d_in[4];
    const float* b1  = (const float*)d_in[5];
    const float* W2  = (const float*)d_in[6];
    const float* as2 = (const float*)d_in[7];
    const float* ad2 = (const float*)d_in[8];
    const float* b2  = (const float*)d_in[9];
    const float* Wl  = (const float*)d_in[10];
    const float* bl  = (const float*)d_in[11];
    float* out = (float*)d_out;

    // ---- workspace layout: ~31 MB (bbuf overlays g1: 9.63 MB <= 12.8 MB) ----
    float* ws = (float*)d_ws;
    size_t o = 0;
    u16* hb  = (u16*)(ws + o); o += (size_t)NN * 64;    // bf16 h1[NN][128] / h2[NN][64]
    u16* g1  = (u16*)(ws + o); o += (size_t)NN * 64;    // bf16 g1 [NN][128]  (= bbuf space)
    unsigned* bbuf = (unsigned*)g1;
    u16* w1t = (u16*)(ws + o); o += 144 * 256 / 2;      // bf16 W1^T+att [144][256]
    u16* w2t = (u16*)(ws + o); o += 80 * 128 / 2;       // bf16 W2^T+att [80][128]
    float* a_s = ws + o;       o += (size_t)NN * 2;
    float* a_d = ws + o;       o += (size_t)NN * 2;
    int* ints = (int*)(ws + o);
    size_t io = 0;
    int* gcursor  = ints + io; io += NBKT;
    int* row_ptr  = ints + io; io += NN + 1;
    u16* csr_src  = (u16*)(ints + io); io += (EP + 1) / 2;

    // ---- CSR build: memset + single edge pass (with setup side jobs) + bucket pass
    hipMemsetAsync(gcursor, 0, NBKT * sizeof(int), stream);
    partition_k<<<NPB, 1024, 0, stream>>>(ei, gcursor, bbuf,
                                          W1, as1, ad1, w1t, W2, as2, ad2, w2t);
    bucket_csr_k<<<NBKT, 1024, 0, stream>>>(bbuf, gcursor, row_ptr, csr_src);

    const int gatherBlocks = (NN + 3) / 4;  // 4 waves (nodes) per 256-thread block
    const int gemmBlocks = (NN + 63) / 64;

    // ---- layer 1: GATConv(256 -> 64, heads=2, concat) + ELU ----
    gemm_mfma_att_k<256, 128, 2, true><<<gemmBlocks, 256, 0, stream>>>(
        x, nullptr, w1t, hb, a_s, a_d);
    gat_gather_k<128, 2, false><<<gatherBlocks, 256, 0, stream>>>(
        row_ptr, csr_src, a_s, a_d, hb, b1, g1, nullptr, nullptr, nullptr);

    // ---- layer 2: GATConv(128 -> 64, heads=1) + ELU + fused head ----
    gemm_mfma_att_k<128, 64, 1, false><<<gemmBlocks, 256, 0, stream>>>(
        nullptr, g1, w2t, hb, a_s, a_d);
    gat_gather_k<64, 1, true><<<gatherBlocks, 256, 0, stream>>>(
        row_ptr, csr_src, a_s, a_d, hb, b2, nullptr, Wl, bl, out);
}